// Round 19
// baseline (206.633 us; speedup 1.0000x reference)
//
#include <hip/hip_runtime.h>
#include <hip/hip_fp16.h>

#define NN 50000
#define EE 800000
#define ETOT 850000          // EE + NN self loops
#define INC 64
#define F1 128               // heads*hidden (4*32)
#define F2 64                // out_channels_gat
#define HL 64                // lstm hidden
#define PO_H 50000           // h-stack base in d_out
#define NHL (NN*HL)
#define PO_C (PO_H + 2*NHL)  // c-stack base

#define NCAP 64              // padded per-node CSR capacity
#define NSEC 64              // sectors
#define SECN 784             // nodes per sector
#define NBLK1 256            // blocks for hist/sfill
#define EPB 3321             // edges per block

typedef _Float16 f16x8 __attribute__((ext_vector_type(8)));
typedef float    f32x4 __attribute__((ext_vector_type(4)));

__device__ __forceinline__ float rcp_(float x){ return __builtin_amdgcn_rcpf(x); }
__device__ __forceinline__ float sigmoidf_(float x){ return rcp_(1.f+__expf(-x)); }
__device__ __forceinline__ float tanhf_(float x){
  x = fminf(8.f, fmaxf(-8.f, x));
  float e = __expf(2.f*x);
  return (e-1.f)*rcp_(e+1.f);
}
__device__ __forceinline__ float lrelu_(float x){ return (x > 0.f) ? x : 0.2f*x; }

// ---------------- CSR build pass 1: per-block sector histogram ----------------
__global__ __launch_bounds__(256) void k_hist(const int* __restrict__ ei, unsigned int* __restrict__ hist){
  __shared__ unsigned int lh[NSEC];
  int b = blockIdx.x;
  if (threadIdx.x < NSEC) lh[threadIdx.x] = 0;
  __syncthreads();
  int beg = b*EPB, end = min(beg+EPB, ETOT);
  for (int t = beg + threadIdx.x; t < end; t += 256){
    int dstv = (t < EE) ? ei[EE + t] : (t - EE);
    atomicAdd(&lh[dstv/SECN], 1u);
  }
  __syncthreads();
  if (threadIdx.x < NSEC) hist[b*NSEC + threadIdx.x] = lh[threadIdx.x];
}

// ---------------- pass 2: scan histogram -> exact (block,sector) offsets ----------------
__global__ __launch_bounds__(1024) void k_hscan(const unsigned int* __restrict__ hist,
    unsigned int* __restrict__ off, unsigned int* __restrict__ secstart){
  __shared__ unsigned int lh[NBLK1*NSEC];
  __shared__ unsigned int sbase[NSEC];
  int tid = threadIdx.x;
  for (int i = tid; i < NBLK1*NSEC; i += 1024) lh[i] = hist[i];
  __syncthreads();
  if (tid < NSEC){
    unsigned int run = 0;
    for (int b = 0; b < NBLK1; b++){
      unsigned int v = lh[b*NSEC + tid];
      lh[b*NSEC + tid] = run;
      run += v;
    }
    unsigned int sc = run;
    for (int o=1;o<64;o<<=1){ unsigned int u=__shfl_up(sc,o,64); if ((tid&63)>=(unsigned)o) sc+=u; }
    sbase[tid] = sc - run;
    secstart[tid] = sc - run;
    if (tid == NSEC-1) secstart[NSEC] = sc;
  }
  __syncthreads();
  for (int i = tid; i < NBLK1*NSEC; i += 1024){
    int s = i & (NSEC-1);
    off[i] = sbase[s] + lh[i];
  }
}

// ---------------- pass 3: dense sector-FIFO fill (no global atomics) ----------------
__global__ __launch_bounds__(256) void k_sfill(const int* __restrict__ ei, const unsigned int* __restrict__ off,
    unsigned int* __restrict__ sfifo){
  __shared__ unsigned int cur[NSEC];
  int b = blockIdx.x;
  if (threadIdx.x < NSEC) cur[threadIdx.x] = off[b*NSEC + threadIdx.x];
  __syncthreads();
  int beg = b*EPB, end = min(beg+EPB, ETOT);
  for (int t = beg + threadIdx.x; t < end; t += 256){
    int srcv, dstv;
    if (t < EE){ srcv = ei[t]; dstv = ei[EE + t]; }
    else       { srcv = t - EE; dstv = t - EE; }
    int s = dstv / SECN;
    unsigned int slot = atomicAdd(&cur[s], 1u);
    sfifo[slot] = (unsigned int)srcv | ((unsigned int)(dstv - s*SECN) << 16);
  }
}

// ---------------- pass 4: sector -> padded CSR entirely in LDS, linear burst out ----------------
__global__ __launch_bounds__(1024) void k_csr(const unsigned int* __restrict__ secstart,
    const unsigned int* __restrict__ sfifo, unsigned short* __restrict__ eidx16, int* __restrict__ deg){
  __shared__ unsigned int ldeg[SECN];
  __shared__ __align__(16) unsigned short lcsr[SECN*NCAP];
  int s = blockIdx.x;
  int tid = threadIdx.x;
  if (tid < SECN) ldeg[tid] = 0;
  __syncthreads();
  unsigned int beg = secstart[s], end = secstart[s+1];
  for (unsigned int i = beg + tid; i < end; i += 1024){
    unsigned int e = sfifo[i];
    int ld = (int)(e >> 16);
    unsigned int slot = atomicAdd(&ldeg[ld], 1u);
    if (slot < NCAP) lcsr[ld*NCAP + slot] = (unsigned short)(e & 0xFFFFu);
  }
  __syncthreads();
  const uint4* src4 = reinterpret_cast<const uint4*>(lcsr);
  uint4* dst4 = reinterpret_cast<uint4*>(eidx16 + (size_t)s*SECN*NCAP);
  for (int i = tid; i < SECN*NCAP/8; i += 1024) dst4[i] = src4[i];
  if (tid < SECN){
    int node = s*SECN + tid;
    if (node < NN) deg[node] = (int)min(ldeg[tid], (unsigned)NCAP);
  }
}

// ---------------- GAT1 GEMM via MFMA (16 nodes/wave), head-major fp16 out + fused s1/d1 ----------------
#define G1W 4
__global__ __launch_bounds__(256) void k_gemm1h(const float* __restrict__ x, const _Float16* __restrict__ W1B,
    const float* __restrict__ as1, const float* __restrict__ ad1,
    _Float16* __restrict__ xwh1, float* __restrict__ s1, float* __restrict__ d1){
  int tid = threadIdx.x, wv = tid >> 6, l = tid & 63;
  int n0 = (blockIdx.x*G1W + wv) * 16;
  if (n0 >= NN) return;
  int lg = l >> 4, lr = l & 15;
  const float* xp = x + (size_t)(n0 + lr)*INC;
  f16x8 a[2];
  #pragma unroll
  for (int kk=0;kk<2;kk++){
    float4 v0 = *reinterpret_cast<const float4*>(&xp[kk*32 + lg*8]);
    float4 v1 = *reinterpret_cast<const float4*>(&xp[kk*32 + lg*8 + 4]);
    a[kk] = (f16x8){ (_Float16)v0.x,(_Float16)v0.y,(_Float16)v0.z,(_Float16)v0.w,
                     (_Float16)v1.x,(_Float16)v1.y,(_Float16)v1.z,(_Float16)v1.w };
  }
  const f16x8* wb = reinterpret_cast<const f16x8*>(W1B);
  f32x4 acc[8];
  #pragma unroll
  for (int t=0;t<8;t++) acc[t] = (f32x4){0.f,0.f,0.f,0.f};
  #pragma unroll
  for (int t=0;t<8;t++){
    #pragma unroll
    for (int kk=0;kk<2;kk++)
      acc[t] = __builtin_amdgcn_mfma_f32_16x16x32_f16(a[kk], wb[(t*2+kk)*64 + l], acc[t], 0, 0, 0);
  }
  float asv[8], adv[8];
  #pragma unroll
  for (int t=0;t<8;t++){ asv[t]=as1[t*16+lr]; adv[t]=ad1[t*16+lr]; }
  #pragma unroll
  for (int q=0;q<4;q++){
    int nq = n0 + lg*4 + q;
    #pragma unroll
    for (int t=0;t<8;t++)     // ch = t*16+lr ; head = t>>1 ; within = (t&1)*16+lr
      xwh1[(size_t)(t>>1)*NN*32 + (size_t)nq*32 + (t&1)*16 + lr] = (_Float16)acc[t][q];
    #pragma unroll
    for (int h=0;h<4;h++){
      float sp = acc[2*h][q]*asv[2*h] + acc[2*h+1][q]*asv[2*h+1];
      float dp = acc[2*h][q]*adv[2*h] + acc[2*h+1][q]*adv[2*h+1];
      sp += __shfl_xor(sp,1,64); sp += __shfl_xor(sp,2,64); sp += __shfl_xor(sp,4,64); sp += __shfl_xor(sp,8,64);
      dp += __shfl_xor(dp,1,64); dp += __shfl_xor(dp,2,64); dp += __shfl_xor(dp,4,64); dp += __shfl_xor(dp,8,64);
      if (lr == 0){ s1[nq*4 + h] = sp; d1[nq*4 + h] = dp; }
    }
  }
}

// ---------------- GAT1 aggregation, HEAD-PHASED: blockIdx = h*12500+blk; L2-resident 3.2MB slice ----------------
__global__ __launch_bounds__(256) void k_agg1p(const _Float16* __restrict__ xwh1, const float* __restrict__ s1,
    const float* __restrict__ d1, const int* __restrict__ deg, const unsigned short* __restrict__ eidx16,
    const float* __restrict__ b1, _Float16* __restrict__ hb16){
  int bid = blockIdx.x;
  int h   = bid / 12500;
  int blk = bid - h*12500;
  int n = blk*4 + (threadIdx.x >> 6);          // < NN exactly
  int lane = threadIdx.x & 63;
  int e4 = lane >> 4, c2 = lane & 15;          // 4 edges x 16 lanes (half2 each)
  const _Float16* tab = xwh1 + (size_t)h*NN*32;
  float dn = d1[n*4 + h];
  int cnt = deg[n], base = n*NCAP;
  float a0=0.f, a1=0.f, sum=0.f;
  int jj = 0;
  for (; jj + 7 < cnt; jj += 8){
    int sA = eidx16[base + jj + e4];
    int sB = eidx16[base + jj + 4 + e4];
    float eA = s1[sA*4 + h] + dn, eB = s1[sB*4 + h] + dn;
    __half2 wA = *reinterpret_cast<const __half2*>(&tab[(size_t)sA*32 + c2*2]);
    __half2 wB = *reinterpret_cast<const __half2*>(&tab[(size_t)sB*32 + c2*2]);
    float xA = __expf(lrelu_(eA)), xB = __expf(lrelu_(eB));
    sum += xA + xB;
    float2 fA = __half22float2(wA), fB = __half22float2(wB);
    a0 += xA*fA.x + xB*fB.x;
    a1 += xA*fA.y + xB*fB.y;
  }
  for (; jj < cnt; jj += 4){
    if (jj + e4 < cnt){
      int s = eidx16[base + jj + e4];
      float e = s1[s*4 + h] + dn;
      __half2 w = *reinterpret_cast<const __half2*>(&tab[(size_t)s*32 + c2*2]);
      float xv = __expf(lrelu_(e));
      sum += xv;
      float2 f = __half22float2(w);
      a0 += xv*f.x; a1 += xv*f.y;
    }
  }
  a0 += __shfl_xor(a0,16,64); a0 += __shfl_xor(a0,32,64);
  a1 += __shfl_xor(a1,16,64); a1 += __shfl_xor(a1,32,64);
  sum += __shfl_xor(sum,16,64); sum += __shfl_xor(sum,32,64);
  if (e4 == 0){
    float inv = rcp_(sum + 1e-16f);
    float r0 = a0*inv + b1[h*32 + c2*2];
    float r1 = a1*inv + b1[h*32 + c2*2 + 1];
    r0 = (r0 > 0.f) ? r0 : (__expf(r0) - 1.f);
    r1 = (r1 > 0.f) ? r1 : (__expf(r1) - 1.f);
    *reinterpret_cast<__half2*>(&hb16[(size_t)n*F1 + h*32 + c2*2]) = __floats2half2_rn(r0, r1);
  }
}

// ---------------- GAT2 GEMM via MFMA (16 nodes/wave), half-major fp16 out + fused s2/d2 ----------------
#define G2W 4
__global__ __launch_bounds__(256) void k_gemm2h(const _Float16* __restrict__ hb16, const _Float16* __restrict__ W2B,
    const float* __restrict__ as2, const float* __restrict__ ad2,
    _Float16* __restrict__ xwh2, float* __restrict__ s2, float* __restrict__ d2){
  int tid = threadIdx.x, wv = tid >> 6, l = tid & 63;
  int n0 = (blockIdx.x*G2W + wv) * 16;
  if (n0 >= NN) return;
  int lg = l >> 4, lr = l & 15;
  const _Float16* hp = hb16 + (size_t)(n0 + lr)*F1;
  f16x8 a[4];
  #pragma unroll
  for (int kk=0;kk<4;kk++)
    a[kk] = *reinterpret_cast<const f16x8*>(&hp[kk*32 + lg*8]);
  const f16x8* wb = reinterpret_cast<const f16x8*>(W2B);
  f32x4 acc[4];
  #pragma unroll
  for (int t=0;t<4;t++) acc[t] = (f32x4){0.f,0.f,0.f,0.f};
  #pragma unroll
  for (int t=0;t<4;t++){
    #pragma unroll
    for (int kk=0;kk<4;kk++)
      acc[t] = __builtin_amdgcn_mfma_f32_16x16x32_f16(a[kk], wb[(t*4+kk)*64 + l], acc[t], 0, 0, 0);
  }
  float sv[4], dv[4];
  #pragma unroll
  for (int t=0;t<4;t++){ sv[t]=as2[t*16+lr]; dv[t]=ad2[t*16+lr]; }
  #pragma unroll
  for (int q=0;q<4;q++){
    int nq = n0 + lg*4 + q;
    float sp=0.f, dp=0.f;
    #pragma unroll
    for (int t=0;t<4;t++){     // ch = t*16+lr ; half = t>>1 ; within = (t&1)*16+lr
      float v = acc[t][q];
      xwh2[(size_t)(t>>1)*NN*32 + (size_t)nq*32 + (t&1)*16 + lr] = (_Float16)v;
      sp += v*sv[t]; dp += v*dv[t];
    }
    sp += __shfl_xor(sp,1,64); sp += __shfl_xor(sp,2,64); sp += __shfl_xor(sp,4,64); sp += __shfl_xor(sp,8,64);
    dp += __shfl_xor(dp,1,64); dp += __shfl_xor(dp,2,64); dp += __shfl_xor(dp,4,64); dp += __shfl_xor(dp,8,64);
    if (lr == 0){ s2[nq] = sp; d2[nq] = dp; }
  }
}

// ---------------- GAT2 aggregation, HALF-PHASED: blockIdx = half*12500+blk; 3.2MB slice ----------------
__global__ __launch_bounds__(256) void k_agg2p(const _Float16* __restrict__ xwh2, const float* __restrict__ s2,
    const float* __restrict__ d2, const int* __restrict__ deg, const unsigned short* __restrict__ eidx16,
    const float* __restrict__ b2, _Float16* __restrict__ gh){
  int bid = blockIdx.x;
  int hf  = bid / 12500;
  int blk = bid - hf*12500;
  int n = blk*4 + (threadIdx.x >> 6);
  int lane = threadIdx.x & 63;
  int e4 = lane >> 4, c2 = lane & 15;
  const _Float16* tab = xwh2 + (size_t)hf*NN*32;
  float dn = d2[n];
  int cnt = deg[n], base = n*NCAP;
  float a0=0.f, a1=0.f, sum=0.f;
  int jj = 0;
  for (; jj + 7 < cnt; jj += 8){
    int sA = eidx16[base + jj + e4];
    int sB = eidx16[base + jj + 4 + e4];
    float eA = s2[sA] + dn, eB = s2[sB] + dn;
    __half2 wA = *reinterpret_cast<const __half2*>(&tab[(size_t)sA*32 + c2*2]);
    __half2 wB = *reinterpret_cast<const __half2*>(&tab[(size_t)sB*32 + c2*2]);
    float xA = __expf(lrelu_(eA)), xB = __expf(lrelu_(eB));
    sum += xA + xB;
    float2 fA = __half22float2(wA), fB = __half22float2(wB);
    a0 += xA*fA.x + xB*fB.x;
    a1 += xA*fA.y + xB*fB.y;
  }
  for (; jj < cnt; jj += 4){
    if (jj + e4 < cnt){
      int s = eidx16[base + jj + e4];
      float e = s2[s] + dn;
      __half2 w = *reinterpret_cast<const __half2*>(&tab[(size_t)s*32 + c2*2]);
      float xv = __expf(lrelu_(e));
      sum += xv;
      float2 f = __half22float2(w);
      a0 += xv*f.x; a1 += xv*f.y;
    }
  }
  a0 += __shfl_xor(a0,16,64); a0 += __shfl_xor(a0,32,64);
  a1 += __shfl_xor(a1,16,64); a1 += __shfl_xor(a1,32,64);
  sum += __shfl_xor(sum,16,64); sum += __shfl_xor(sum,32,64);
  if (e4 == 0){
    float inv = rcp_(sum + 1e-16f);
    float r0 = a0*inv + b2[hf*32 + c2*2];
    float r1 = a1*inv + b2[hf*32 + c2*2 + 1];
    *reinterpret_cast<__half2*>(&gh[(size_t)n*F2 + hf*32 + c2*2]) = __floats2half2_rn(r0, r1);
  }
}

// ---------------- weight pack: LSTM B-fragments + bias sums + W2/W1 B-fragments ----------------
__global__ void k_wt3(const float* __restrict__ Wih0, const float* __restrict__ Wih1,
                      const float* __restrict__ bih0, const float* __restrict__ bhh0,
                      const float* __restrict__ bih1, const float* __restrict__ bhh1,
                      const float* __restrict__ W2, const float* __restrict__ W1,
                      _Float16* __restrict__ Wpk, float* __restrict__ bsum,
                      _Float16* __restrict__ W2B, _Float16* __restrict__ W1B){
  int t = blockIdx.x*256 + threadIdx.x;
  if (t < 24576){
    int j = t & 7;
    int lane = (t >> 3) & 63;
    int rest = t >> 9;
    int kh = rest & 1; rest >>= 1;
    int tt = rest % 12;
    int cell = rest / 12;
    int gate = tt*16 + (lane & 15);
    int row = (gate < 64) ? gate : gate + 64;
    int c = kh*32 + ((lane >> 4) & 3)*8 + j;
    const float* W = cell ? Wih1 : Wih0;
    Wpk[t] = (_Float16)W[row*64 + c];
  } else if (t < 24576 + 384){
    int u = t - 24576;
    int cell = u / 192, gate = u % 192;
    int row = (gate < 64) ? gate : gate + 64;
    bsum[u] = cell ? (bih1[row] + bhh1[row]) : (bih0[row] + bhh0[row]);
  } else if (t < 24960 + 8192){
    int u = t - 24960;
    int j = u & 7;
    int lane = (u >> 3) & 63;
    int tile = u >> 9;
    int tcol = tile >> 2, kk = tile & 3;
    int k = kk*32 + ((lane >> 4) & 3)*8 + j;
    int col = tcol*16 + (lane & 15);
    W2B[u] = (_Float16)W2[k*F2 + col];
  } else if (t < 33152 + 8192){
    int u = t - 33152;
    int j = u & 7;
    int lane = (u >> 3) & 63;
    int tile = u >> 9;
    int tcol = tile >> 1, kk = tile & 1;
    int k = kk*32 + ((lane >> 4) & 3)*8 + j;
    int col = tcol*16 + (lane & 15);
    W1B[u] = (_Float16)W1[k*F1 + col];
  }
}

// ---------------- fused LSTM x2 + projection via MFMA (16 nodes/wave, 4 waves/block), fp16 g in ----------------
#define L6N 16
#define L6W 4
__global__ __launch_bounds__(256) void k_lstm6(const _Float16* __restrict__ gh,
    const _Float16* __restrict__ Wpk, const float* __restrict__ bsum,
    const float* __restrict__ Wo, const float* __restrict__ bo, float* __restrict__ out){
  __shared__ _Float16 hlds[L6W][16][72];
  int tid = threadIdx.x;
  int wv = tid >> 6, l = tid & 63;
  int n0 = (blockIdx.x*L6W + wv) * L6N;
  int lg = l >> 4;
  int lr = l & 15;

  float wo_t[4];
  #pragma unroll
  for (int t=0;t<4;t++) wo_t[t] = Wo[t*16 + lr];
  float bov = bo[0];

  int gn = min(n0 + lr, NN-1);
  const _Float16* gp = &gh[(size_t)gn*HL];
  f16x8 a0 = *reinterpret_cast<const f16x8*>(&gp[lg*8]);
  f16x8 a1 = *reinterpret_cast<const f16x8*>(&gp[32 + lg*8]);

  const f16x8* wp = reinterpret_cast<const f16x8*>(Wpk);

  f32x4 acc[12];
  #pragma unroll
  for (int t=0;t<12;t++){
    float b = bsum[t*16 + lr];
    acc[t] = (f32x4){b,b,b,b};
  }
  #pragma unroll
  for (int t=0;t<12;t++){
    f16x8 b0 = wp[(t*2+0)*64 + l];
    f16x8 b1 = wp[(t*2+1)*64 + l];
    acc[t] = __builtin_amdgcn_mfma_f32_16x16x32_f16(a0, b0, acc[t], 0, 0, 0);
    acc[t] = __builtin_amdgcn_mfma_f32_16x16x32_f16(a1, b1, acc[t], 0, 0, 0);
  }

  #pragma unroll
  for (int q=0;q<4;q++){
    int n = n0 + lg*4 + q;
    bool ok = n < NN;
    #pragma unroll
    for (int t=0;t<4;t++){
      float iv = acc[t][q], gv = acc[4+t][q], ov = acc[8+t][q];
      float cc = sigmoidf_(iv)*tanhf_(gv);
      float hh = sigmoidf_(ov)*tanhf_(cc);
      int ch = t*16 + lr;
      if (ok){
        out[PO_H + n*HL + ch] = hh;
        out[PO_C + n*HL + ch] = cc;
      }
      hlds[wv][lg*4+q][ch] = (_Float16)hh;
    }
  }
  __syncthreads();

  f16x8 ha0 = *reinterpret_cast<const f16x8*>(&hlds[wv][lr][lg*8]);
  f16x8 ha1 = *reinterpret_cast<const f16x8*>(&hlds[wv][lr][32 + lg*8]);

  #pragma unroll
  for (int t=0;t<12;t++){
    float b = bsum[192 + t*16 + lr];
    acc[t] = (f32x4){b,b,b,b};
  }
  #pragma unroll
  for (int t=0;t<12;t++){
    f16x8 b0 = wp[(24 + t*2+0)*64 + l];
    f16x8 b1 = wp[(24 + t*2+1)*64 + l];
    acc[t] = __builtin_amdgcn_mfma_f32_16x16x32_f16(ha0, b0, acc[t], 0, 0, 0);
    acc[t] = __builtin_amdgcn_mfma_f32_16x16x32_f16(ha1, b1, acc[t], 0, 0, 0);
  }

  #pragma unroll
  for (int q=0;q<4;q++){
    int n = n0 + lg*4 + q;
    bool ok = n < NN;
    float p = 0.f;
    #pragma unroll
    for (int t=0;t<4;t++){
      float iv = acc[t][q], gv = acc[4+t][q], ov = acc[8+t][q];
      float cc = sigmoidf_(iv)*tanhf_(gv);
      float hh = sigmoidf_(ov)*tanhf_(cc);
      int ch = t*16 + lr;
      if (ok){
        out[PO_H + NHL + n*HL + ch] = hh;
        out[PO_C + NHL + n*HL + ch] = cc;
      }
      p += hh * wo_t[t];
    }
    p += __shfl_xor(p, 1, 64);
    p += __shfl_xor(p, 2, 64);
    p += __shfl_xor(p, 4, 64);
    p += __shfl_xor(p, 8, 64);
    if (lr == 0 && ok) out[n] = p + bov;
  }
}

extern "C" void kernel_launch(void* const* d_in, const int* in_sizes, int n_in,
                              void* d_out, int out_size, void* d_ws, size_t ws_size,
                              hipStream_t stream){
  const float* x    = (const float*)d_in[0];
  const int*   ei   = (const int*)d_in[1];
  const float* W1   = (const float*)d_in[3];
  const float* as1  = (const float*)d_in[4];
  const float* ad1  = (const float*)d_in[5];
  const float* b1   = (const float*)d_in[6];
  const float* W2   = (const float*)d_in[7];
  const float* as2  = (const float*)d_in[8];
  const float* ad2  = (const float*)d_in[9];
  const float* b2   = (const float*)d_in[10];
  const float* Wih0 = (const float*)d_in[11];
  const float* bih0 = (const float*)d_in[13];
  const float* bhh0 = (const float*)d_in[14];
  const float* Wih1 = (const float*)d_in[15];
  const float* bih1 = (const float*)d_in[17];
  const float* bhh1 = (const float*)d_in[18];
  const float* Wo   = (const float*)d_in[19];
  const float* bo   = (const float*)d_in[20];
  float* out = (float*)d_out;

  float* ws   = (float*)d_ws;
  // layout (float offsets):
  _Float16* xwh1 = (_Float16*)ws;                    // [0, 3.2M) : 4 slices x 3.2MB (dead after agg1p)
  __half*   gh   = (__half*)ws;                      // [0, 0.8M) : agg2p out (xwh1 dead then)
  unsigned int* sfifo = (unsigned int*)(ws + 3200000); // [3.2M, 4.05M) : dead after k_csr
  _Float16* xwh2 = (_Float16*)(ws + 3200000);        // [3.2M, 4.8M) : 2 slices x 3.2MB (gemm2h out)
  _Float16* hb16 = (_Float16*)(ws + 4800000);        // [4.8M, 8.0M) : agg1p out
  float* s1   = ws + 9600000;                        // 200,000
  float* d1   = s1 + 200000;                         // -> 10.0M
  float* s2   = ws + 10000000;                       // 50,000
  float* d2   = s2 + 50000;                          // 50,000
  int*   deg  = (int*)(ws + 10100000);               // 50,000
  unsigned int* hist = (unsigned int*)(ws + 10150000);     // 16,384
  unsigned int* off  = (unsigned int*)(ws + 10170000);     // 16,384
  unsigned int* secstart = (unsigned int*)(ws + 10190000); // 65
  unsigned short* eidx16 = (unsigned short*)(ws + 10200000); // -> 11.81M
  _Float16* Wpk = (_Float16*)(ws + 11810000);        // 24,576 halves
  float* bsum = ws + 11823000;                       // 384 floats
  _Float16* W2B = (_Float16*)(ws + 11824000);        // 8,192 halves
  _Float16* W1B = (_Float16*)(ws + 11828096);        // 8,192 halves (end ~47.3 MB)

  k_hist  <<<NBLK1, 256, 0, stream>>>(ei, hist);
  k_hscan <<<1, 1024, 0, stream>>>(hist, off, secstart);
  k_sfill <<<NBLK1, 256, 0, stream>>>(ei, off, sfifo);
  k_csr   <<<NSEC, 1024, 0, stream>>>(secstart, sfifo, eidx16, deg);
  k_wt3   <<<162, 256, 0, stream>>>(Wih0, Wih1, bih0, bhh0, bih1, bhh1, W2, W1, Wpk, bsum, W2B, W1B);
  k_gemm1h<<<(NN/16 + G1W - 1)/G1W, 256, 0, stream>>>(x, W1B, as1, ad1, xwh1, s1, d1);
  k_agg1p <<<4*12500, 256, 0, stream>>>(xwh1, s1, d1, deg, eidx16, b1, hb16);
  k_gemm2h<<<(NN/16 + G2W - 1)/G2W, 256, 0, stream>>>(hb16, W2B, as2, ad2, xwh2, s2, d2);
  k_agg2p <<<2*12500, 256, 0, stream>>>(xwh2, s2, d2, deg, eidx16, b2, (_Float16*)gh);
  k_lstm6 <<<(NN + L6W*L6N - 1)/(L6W*L6N), 256, 0, stream>>>((const _Float16*)gh, Wpk, bsum, Wo, bo, out);
}

// Round 20
// 144.862 us; speedup vs baseline: 1.4264x; 1.4264x over previous
//
#include <hip/hip_runtime.h>
#include <hip/hip_fp16.h>

#define NN 50000
#define EE 800000
#define ETOT 850000          // EE + NN self loops
#define INC 64
#define F1 128               // heads*hidden (4*32)
#define F2 64                // out_channels_gat
#define HL 64                // lstm hidden
#define PO_H 50000           // h-stack base in d_out
#define NHL (NN*HL)
#define PO_C (PO_H + 2*NHL)  // c-stack base

#define NCAP 64              // padded per-node CSR capacity (mean deg 17, P(>63)~1e-15)
#define NSEC 64              // sectors
#define SECN 784             // nodes per sector (64*784 = 50176 >= NN)
#define NBLK1 256            // blocks for hist/sfill
#define EPB 3321             // edges per block (256*3321 >= ETOT)

typedef _Float16 f16x8 __attribute__((ext_vector_type(8)));
typedef float    f32x4 __attribute__((ext_vector_type(4)));

__device__ __forceinline__ float rcp_(float x){ return __builtin_amdgcn_rcpf(x); }
__device__ __forceinline__ float sigmoidf_(float x){ return rcp_(1.f+__expf(-x)); }
__device__ __forceinline__ float tanhf_(float x){
  x = fminf(8.f, fmaxf(-8.f, x));
  float e = __expf(2.f*x);
  return (e-1.f)*rcp_(e+1.f);
}
__device__ __forceinline__ float lrelu_(float x){ return (x > 0.f) ? x : 0.2f*x; }

// ---------------- CSR build pass 1: per-block sector histogram ----------------
__global__ __launch_bounds__(256) void k_hist(const int* __restrict__ ei, unsigned int* __restrict__ hist){
  __shared__ unsigned int lh[NSEC];
  int b = blockIdx.x;
  if (threadIdx.x < NSEC) lh[threadIdx.x] = 0;
  __syncthreads();
  int beg = b*EPB, end = min(beg+EPB, ETOT);
  for (int t = beg + threadIdx.x; t < end; t += 256){
    int dstv = (t < EE) ? ei[EE + t] : (t - EE);
    atomicAdd(&lh[dstv/SECN], 1u);
  }
  __syncthreads();
  if (threadIdx.x < NSEC) hist[b*NSEC + threadIdx.x] = lh[threadIdx.x];
}

// ---------------- pass 2: scan histogram -> exact (block,sector) offsets ----------------
__global__ __launch_bounds__(1024) void k_hscan(const unsigned int* __restrict__ hist,
    unsigned int* __restrict__ off, unsigned int* __restrict__ secstart){
  __shared__ unsigned int lh[NBLK1*NSEC];
  __shared__ unsigned int sbase[NSEC];
  int tid = threadIdx.x;
  for (int i = tid; i < NBLK1*NSEC; i += 1024) lh[i] = hist[i];
  __syncthreads();
  if (tid < NSEC){
    unsigned int run = 0;
    for (int b = 0; b < NBLK1; b++){
      unsigned int v = lh[b*NSEC + tid];
      lh[b*NSEC + tid] = run;
      run += v;
    }
    unsigned int sc = run;
    for (int o=1;o<64;o<<=1){ unsigned int u=__shfl_up(sc,o,64); if ((tid&63)>=(unsigned)o) sc+=u; }
    sbase[tid] = sc - run;
    secstart[tid] = sc - run;
    if (tid == NSEC-1) secstart[NSEC] = sc;
  }
  __syncthreads();
  for (int i = tid; i < NBLK1*NSEC; i += 1024){
    int s = i & (NSEC-1);
    off[i] = sbase[s] + lh[i];
  }
}

// ---------------- pass 3: dense sector-FIFO fill (no global atomics) ----------------
__global__ __launch_bounds__(256) void k_sfill(const int* __restrict__ ei, const unsigned int* __restrict__ off,
    unsigned int* __restrict__ sfifo){
  __shared__ unsigned int cur[NSEC];
  int b = blockIdx.x;
  if (threadIdx.x < NSEC) cur[threadIdx.x] = off[b*NSEC + threadIdx.x];
  __syncthreads();
  int beg = b*EPB, end = min(beg+EPB, ETOT);
  for (int t = beg + threadIdx.x; t < end; t += 256){
    int srcv, dstv;
    if (t < EE){ srcv = ei[t]; dstv = ei[EE + t]; }
    else       { srcv = t - EE; dstv = t - EE; }
    int s = dstv / SECN;
    unsigned int slot = atomicAdd(&cur[s], 1u);
    sfifo[slot] = (unsigned int)srcv | ((unsigned int)(dstv - s*SECN) << 16);
  }
}

// ---------------- pass 4: sector -> padded CSR entirely in LDS, linear burst out ----------------
__global__ __launch_bounds__(1024) void k_csr(const unsigned int* __restrict__ secstart,
    const unsigned int* __restrict__ sfifo, unsigned short* __restrict__ eidx16, int* __restrict__ deg){
  __shared__ unsigned int ldeg[SECN];
  __shared__ __align__(16) unsigned short lcsr[SECN*NCAP];
  int s = blockIdx.x;
  int tid = threadIdx.x;
  if (tid < SECN) ldeg[tid] = 0;
  __syncthreads();
  unsigned int beg = secstart[s], end = secstart[s+1];
  for (unsigned int i = beg + tid; i < end; i += 1024){
    unsigned int e = sfifo[i];
    int ld = (int)(e >> 16);
    unsigned int slot = atomicAdd(&ldeg[ld], 1u);
    if (slot < NCAP) lcsr[ld*NCAP + slot] = (unsigned short)(e & 0xFFFFu);
  }
  __syncthreads();
  const uint4* src4 = reinterpret_cast<const uint4*>(lcsr);
  uint4* dst4 = reinterpret_cast<uint4*>(eidx16 + (size_t)s*SECN*NCAP);
  for (int i = tid; i < SECN*NCAP/8; i += 1024) dst4[i] = src4[i];
  if (tid < SECN){
    int node = s*SECN + tid;
    if (node < NN) deg[node] = (int)min(ldeg[tid], (unsigned)NCAP);
  }
}

// ---------------- GAT1 GEMM via MFMA: xw1 = x@W1 (16 nodes/wave) + fused s1/d1 ----------------
#define G1W 4
__global__ __launch_bounds__(256) void k_gemm1h(const float* __restrict__ x, const _Float16* __restrict__ W1B,
    const float* __restrict__ as1, const float* __restrict__ ad1,
    __half* __restrict__ xw1h, float* __restrict__ s1, float* __restrict__ d1){
  int tid = threadIdx.x, wv = tid >> 6, l = tid & 63;
  int n0 = (blockIdx.x*G1W + wv) * 16;
  if (n0 >= NN) return;                      // NN = 3125*16 exactly
  int lg = l >> 4, lr = l & 15;
  const float* xp = x + (size_t)(n0 + lr)*INC;
  f16x8 a[2];
  #pragma unroll
  for (int kk=0;kk<2;kk++){
    float4 v0 = *reinterpret_cast<const float4*>(&xp[kk*32 + lg*8]);
    float4 v1 = *reinterpret_cast<const float4*>(&xp[kk*32 + lg*8 + 4]);
    a[kk] = (f16x8){ (_Float16)v0.x,(_Float16)v0.y,(_Float16)v0.z,(_Float16)v0.w,
                     (_Float16)v1.x,(_Float16)v1.y,(_Float16)v1.z,(_Float16)v1.w };
  }
  const f16x8* wb = reinterpret_cast<const f16x8*>(W1B);
  f32x4 acc[8];
  #pragma unroll
  for (int t=0;t<8;t++) acc[t] = (f32x4){0.f,0.f,0.f,0.f};
  #pragma unroll
  for (int t=0;t<8;t++){
    #pragma unroll
    for (int kk=0;kk<2;kk++)
      acc[t] = __builtin_amdgcn_mfma_f32_16x16x32_f16(a[kk], wb[(t*2+kk)*64 + l], acc[t], 0, 0, 0);
  }
  float asv[8], adv[8];
  #pragma unroll
  for (int t=0;t<8;t++){ asv[t]=as1[t*16+lr]; adv[t]=ad1[t*16+lr]; }
  #pragma unroll
  for (int q=0;q<4;q++){
    int nq = n0 + lg*4 + q;
    #pragma unroll
    for (int t=0;t<8;t++)
      xw1h[nq*F1 + t*16 + lr] = __float2half(acc[t][q]);
    #pragma unroll
    for (int h=0;h<4;h++){
      float sp = acc[2*h][q]*asv[2*h] + acc[2*h+1][q]*asv[2*h+1];
      float dp = acc[2*h][q]*adv[2*h] + acc[2*h+1][q]*adv[2*h+1];
      sp += __shfl_xor(sp,1,64); sp += __shfl_xor(sp,2,64); sp += __shfl_xor(sp,4,64); sp += __shfl_xor(sp,8,64);
      dp += __shfl_xor(dp,1,64); dp += __shfl_xor(dp,2,64); dp += __shfl_xor(dp,4,64); dp += __shfl_xor(dp,8,64);
      if (lr == 0){ s1[nq*4 + h] = sp; d1[nq*4 + h] = dp; }
    }
  }
}

// ---------------- GAT1 aggregation (wave per node), padded-CSR, 8x MLP, fused bias+ELU, fp16 h out ----------------
__global__ __launch_bounds__(256) void k_agg1(const __half2* __restrict__ xw1h, const float* __restrict__ s1,
    const float* __restrict__ d1, const int* __restrict__ deg, const unsigned short* __restrict__ eidx16,
    const float* __restrict__ b1, __half* __restrict__ hb16){
  int n = blockIdx.x*4 + (threadIdx.x >> 6);   // 12500*4 == NN
  int lane = threadIdx.x & 63;
  int h = lane >> 4;
  float dn = d1[n*4 + h];
  int cnt = deg[n];
  int base = n*NCAP;
  float acc0=0.f, acc1=0.f, sum=0.f;
  int jj = 0;
  for (; jj + 7 < cnt; jj += 8){
    ushort4 qa = *reinterpret_cast<const ushort4*>(&eidx16[base + jj]);
    ushort4 qb = *reinterpret_cast<const ushort4*>(&eidx16[base + jj + 4]);
    int i0=qa.x, i1=qa.y, i2=qa.z, i3=qa.w, i4=qb.x, i5=qb.y, i6=qb.z, i7=qb.w;
    float e0=s1[i0*4+h], e1=s1[i1*4+h], e2=s1[i2*4+h], e3=s1[i3*4+h];
    float e4=s1[i4*4+h], e5=s1[i5*4+h], e6=s1[i6*4+h], e7=s1[i7*4+h];
    __half2 w0=xw1h[i0*64+lane], w1=xw1h[i1*64+lane], w2=xw1h[i2*64+lane], w3=xw1h[i3*64+lane];
    __half2 w4=xw1h[i4*64+lane], w5=xw1h[i5*64+lane], w6=xw1h[i6*64+lane], w7=xw1h[i7*64+lane];
    float x0=__expf(lrelu_(e0+dn)), x1=__expf(lrelu_(e1+dn)), x2=__expf(lrelu_(e2+dn)), x3=__expf(lrelu_(e3+dn));
    float x4=__expf(lrelu_(e4+dn)), x5=__expf(lrelu_(e5+dn)), x6=__expf(lrelu_(e6+dn)), x7=__expf(lrelu_(e7+dn));
    sum += ((x0+x1)+(x2+x3)) + ((x4+x5)+(x6+x7));
    float2 f0=__half22float2(w0), f1=__half22float2(w1), f2=__half22float2(w2), f3=__half22float2(w3);
    float2 f4=__half22float2(w4), f5=__half22float2(w5), f6=__half22float2(w6), f7=__half22float2(w7);
    acc0 += (x0*f0.x + x1*f1.x + x2*f2.x + x3*f3.x) + (x4*f4.x + x5*f5.x + x6*f6.x + x7*f7.x);
    acc1 += (x0*f0.y + x1*f1.y + x2*f2.y + x3*f3.y) + (x4*f4.y + x5*f5.y + x6*f6.y + x7*f7.y);
  }
  for (; jj + 3 < cnt; jj += 4){
    ushort4 q = *reinterpret_cast<const ushort4*>(&eidx16[base + jj]);
    int i0=q.x, i1=q.y, i2=q.z, i3=q.w;
    float e0=s1[i0*4+h], e1=s1[i1*4+h], e2=s1[i2*4+h], e3=s1[i3*4+h];
    __half2 w0=xw1h[i0*64+lane], w1=xw1h[i1*64+lane], w2=xw1h[i2*64+lane], w3=xw1h[i3*64+lane];
    float x0=__expf(lrelu_(e0+dn)), x1=__expf(lrelu_(e1+dn)), x2=__expf(lrelu_(e2+dn)), x3=__expf(lrelu_(e3+dn));
    sum += (x0+x1)+(x2+x3);
    float2 f0=__half22float2(w0), f1=__half22float2(w1), f2=__half22float2(w2), f3=__half22float2(w3);
    acc0 += x0*f0.x + x1*f1.x + x2*f2.x + x3*f3.x;
    acc1 += x0*f0.y + x1*f1.y + x2*f2.y + x3*f3.y;
  }
  for (; jj < cnt; ++jj){
    int src = eidx16[base + jj];
    float ex = __expf(lrelu_(s1[src*4+h]+dn));
    sum += ex;
    float2 f = __half22float2(xw1h[src*64+lane]);
    acc0 += ex*f.x; acc1 += ex*f.y;
  }
  float inv = rcp_(sum + 1e-16f);
  float r0 = acc0*inv + b1[lane*2];
  float r1 = acc1*inv + b1[lane*2+1];
  r0 = (r0 > 0.f) ? r0 : (__expf(r0) - 1.f);   // ELU
  r1 = (r1 > 0.f) ? r1 : (__expf(r1) - 1.f);
  *reinterpret_cast<__half2*>(&hb16[n*F1 + lane*2]) = __floats2half2_rn(r0, r1);
}

// ---------------- GAT2 GEMM via MFMA: xw2 = h@W2 (16 nodes/wave) + fused s2/d2 ----------------
#define G2W 4
__global__ __launch_bounds__(256) void k_gemm2h(const _Float16* __restrict__ hb16, const _Float16* __restrict__ W2B,
    const float* __restrict__ as2, const float* __restrict__ ad2,
    __half* __restrict__ xw2h, float* __restrict__ s2, float* __restrict__ d2){
  int tid = threadIdx.x, wv = tid >> 6, l = tid & 63;
  int n0 = (blockIdx.x*G2W + wv) * 16;
  if (n0 >= NN) return;                      // NN = 3125*16, full waves only
  int lg = l >> 4, lr = l & 15;
  const _Float16* hp = hb16 + (size_t)(n0 + lr)*F1;
  f16x8 a[4];
  #pragma unroll
  for (int kk=0;kk<4;kk++)
    a[kk] = *reinterpret_cast<const f16x8*>(&hp[kk*32 + lg*8]);
  const f16x8* wb = reinterpret_cast<const f16x8*>(W2B);
  f32x4 acc[4];
  #pragma unroll
  for (int t=0;t<4;t++) acc[t] = (f32x4){0.f,0.f,0.f,0.f};
  #pragma unroll
  for (int t=0;t<4;t++){
    #pragma unroll
    for (int kk=0;kk<4;kk++)
      acc[t] = __builtin_amdgcn_mfma_f32_16x16x32_f16(a[kk], wb[(t*4+kk)*64 + l], acc[t], 0, 0, 0);
  }
  float sv[4], dv[4];
  #pragma unroll
  for (int t=0;t<4;t++){ sv[t]=as2[t*16+lr]; dv[t]=ad2[t*16+lr]; }
  #pragma unroll
  for (int q=0;q<4;q++){
    int nq = n0 + lg*4 + q;
    float sp=0.f, dp=0.f;
    #pragma unroll
    for (int t=0;t<4;t++){
      float v = acc[t][q];
      xw2h[nq*F2 + t*16 + lr] = __float2half(v);
      sp += v*sv[t]; dp += v*dv[t];
    }
    sp += __shfl_xor(sp,1,64); sp += __shfl_xor(sp,2,64); sp += __shfl_xor(sp,4,64); sp += __shfl_xor(sp,8,64);
    dp += __shfl_xor(dp,1,64); dp += __shfl_xor(dp,2,64); dp += __shfl_xor(dp,4,64); dp += __shfl_xor(dp,8,64);
    if (lr == 0){ s2[nq] = sp; d2[nq] = dp; }
  }
}

// ---------------- GAT layer 2 aggregation (wave per node), padded-CSR, 8x MLP, fused bias ----------------
__global__ __launch_bounds__(256) void k_agg2(const __half* __restrict__ xw2h, const float* __restrict__ s2,
    const float* __restrict__ d2, const int* __restrict__ deg, const unsigned short* __restrict__ eidx16,
    const float* __restrict__ b2, float* __restrict__ gbuf){
  int n = blockIdx.x*4 + (threadIdx.x >> 6);
  if (n >= NN) return;
  int lane = threadIdx.x & 63;
  float dn = d2[n];
  int cnt = deg[n];
  int base = n*NCAP;
  float acc=0.f, sum=0.f;
  int jj = 0;
  for (; jj + 7 < cnt; jj += 8){
    ushort4 qa = *reinterpret_cast<const ushort4*>(&eidx16[base + jj]);
    ushort4 qb = *reinterpret_cast<const ushort4*>(&eidx16[base + jj + 4]);
    int i0=qa.x, i1=qa.y, i2=qa.z, i3=qa.w, i4=qb.x, i5=qb.y, i6=qb.z, i7=qb.w;
    float e0=s2[i0], e1=s2[i1], e2=s2[i2], e3=s2[i3];
    float e4=s2[i4], e5=s2[i5], e6=s2[i6], e7=s2[i7];
    __half w0=xw2h[i0*64+lane], w1=xw2h[i1*64+lane], w2=xw2h[i2*64+lane], w3=xw2h[i3*64+lane];
    __half w4=xw2h[i4*64+lane], w5=xw2h[i5*64+lane], w6=xw2h[i6*64+lane], w7=xw2h[i7*64+lane];
    float x0=__expf(lrelu_(e0+dn)), x1=__expf(lrelu_(e1+dn)), x2=__expf(lrelu_(e2+dn)), x3=__expf(lrelu_(e3+dn));
    float x4=__expf(lrelu_(e4+dn)), x5=__expf(lrelu_(e5+dn)), x6=__expf(lrelu_(e6+dn)), x7=__expf(lrelu_(e7+dn));
    sum += ((x0+x1)+(x2+x3)) + ((x4+x5)+(x6+x7));
    acc += (x0*__half2float(w0) + x1*__half2float(w1) + x2*__half2float(w2) + x3*__half2float(w3))
         + (x4*__half2float(w4) + x5*__half2float(w5) + x6*__half2float(w6) + x7*__half2float(w7));
  }
  for (; jj + 3 < cnt; jj += 4){
    ushort4 q = *reinterpret_cast<const ushort4*>(&eidx16[base + jj]);
    int i0=q.x, i1=q.y, i2=q.z, i3=q.w;
    float e0=s2[i0], e1=s2[i1], e2=s2[i2], e3=s2[i3];
    __half w0=xw2h[i0*64+lane], w1=xw2h[i1*64+lane], w2=xw2h[i2*64+lane], w3=xw2h[i3*64+lane];
    float x0=__expf(lrelu_(e0+dn)), x1=__expf(lrelu_(e1+dn)), x2=__expf(lrelu_(e2+dn)), x3=__expf(lrelu_(e3+dn));
    sum += (x0+x1)+(x2+x3);
    acc += x0*__half2float(w0) + x1*__half2float(w1) + x2*__half2float(w2) + x3*__half2float(w3);
  }
  for (; jj < cnt; ++jj){
    int src = eidx16[base + jj];
    float ex = __expf(lrelu_(s2[src]+dn));
    sum += ex;
    acc += ex * __half2float(xw2h[src*64+lane]);
  }
  gbuf[n*F2 + lane] = acc*rcp_(sum + 1e-16f) + b2[lane];
}

// ---------------- weight pack: LSTM B-fragments + bias sums + W2/W1 B-fragments ----------------
__global__ void k_wt3(const float* __restrict__ Wih0, const float* __restrict__ Wih1,
                      const float* __restrict__ bih0, const float* __restrict__ bhh0,
                      const float* __restrict__ bih1, const float* __restrict__ bhh1,
                      const float* __restrict__ W2, const float* __restrict__ W1,
                      _Float16* __restrict__ Wpk, float* __restrict__ bsum,
                      _Float16* __restrict__ W2B, _Float16* __restrict__ W1B){
  int t = blockIdx.x*256 + threadIdx.x;
  if (t < 24576){
    int j = t & 7;
    int lane = (t >> 3) & 63;
    int rest = t >> 9;
    int kh = rest & 1; rest >>= 1;
    int tt = rest % 12;
    int cell = rest / 12;
    int gate = tt*16 + (lane & 15);
    int row = (gate < 64) ? gate : gate + 64;
    int c = kh*32 + ((lane >> 4) & 3)*8 + j;
    const float* W = cell ? Wih1 : Wih0;
    Wpk[t] = (_Float16)W[row*64 + c];
  } else if (t < 24576 + 384){
    int u = t - 24576;
    int cell = u / 192, gate = u % 192;
    int row = (gate < 64) ? gate : gate + 64;
    bsum[u] = cell ? (bih1[row] + bhh1[row]) : (bih0[row] + bhh0[row]);
  } else if (t < 24960 + 8192){
    int u = t - 24960;                 // tile = tcol*4+kk (F2 tiles, K=128)
    int j = u & 7;
    int lane = (u >> 3) & 63;
    int tile = u >> 9;
    int tcol = tile >> 2, kk = tile & 3;
    int k = kk*32 + ((lane >> 4) & 3)*8 + j;
    int col = tcol*16 + (lane & 15);
    W2B[u] = (_Float16)W2[k*F2 + col];
  } else if (t < 33152 + 8192){
    int u = t - 33152;                 // tile = tcol*2+kk (F1=128 tiles, K=64)
    int j = u & 7;
    int lane = (u >> 3) & 63;
    int tile = u >> 9;
    int tcol = tile >> 1, kk = tile & 1;
    int k = kk*32 + ((lane >> 4) & 3)*8 + j;
    int col = tcol*16 + (lane & 15);
    W1B[u] = (_Float16)W1[k*F1 + col];
  }
}

// ---------------- fused LSTM x2 + projection via MFMA (16 nodes/wave, 4 waves/block) ----------------
#define L6N 16
#define L6W 4
__global__ __launch_bounds__(256) void k_lstm6(const float* __restrict__ g,
    const _Float16* __restrict__ Wpk, const float* __restrict__ bsum,
    const float* __restrict__ Wo, const float* __restrict__ bo, float* __restrict__ out){
  __shared__ _Float16 hlds[L6W][16][72];
  int tid = threadIdx.x;
  int wv = tid >> 6, l = tid & 63;
  int n0 = (blockIdx.x*L6W + wv) * L6N;
  int lg = l >> 4;
  int lr = l & 15;

  float wo_t[4];
  #pragma unroll
  for (int t=0;t<4;t++) wo_t[t] = Wo[t*16 + lr];
  float bov = bo[0];

  int gn = min(n0 + lr, NN-1);
  const float* gp = &g[gn*HL];
  float4 v0 = *reinterpret_cast<const float4*>(&gp[lg*8]);
  float4 v1 = *reinterpret_cast<const float4*>(&gp[lg*8+4]);
  float4 v2 = *reinterpret_cast<const float4*>(&gp[32+lg*8]);
  float4 v3 = *reinterpret_cast<const float4*>(&gp[32+lg*8+4]);
  f16x8 a0 = { (_Float16)v0.x,(_Float16)v0.y,(_Float16)v0.z,(_Float16)v0.w,
               (_Float16)v1.x,(_Float16)v1.y,(_Float16)v1.z,(_Float16)v1.w };
  f16x8 a1 = { (_Float16)v2.x,(_Float16)v2.y,(_Float16)v2.z,(_Float16)v2.w,
               (_Float16)v3.x,(_Float16)v3.y,(_Float16)v3.z,(_Float16)v3.w };

  const f16x8* wp = reinterpret_cast<const f16x8*>(Wpk);

  f32x4 acc[12];
  #pragma unroll
  for (int t=0;t<12;t++){
    float b = bsum[t*16 + lr];
    acc[t] = (f32x4){b,b,b,b};
  }
  #pragma unroll
  for (int t=0;t<12;t++){
    f16x8 b0 = wp[(t*2+0)*64 + l];
    f16x8 b1 = wp[(t*2+1)*64 + l];
    acc[t] = __builtin_amdgcn_mfma_f32_16x16x32_f16(a0, b0, acc[t], 0, 0, 0);
    acc[t] = __builtin_amdgcn_mfma_f32_16x16x32_f16(a1, b1, acc[t], 0, 0, 0);
  }

  #pragma unroll
  for (int q=0;q<4;q++){
    int n = n0 + lg*4 + q;
    bool ok = n < NN;
    #pragma unroll
    for (int t=0;t<4;t++){
      float iv = acc[t][q], gv = acc[4+t][q], ov = acc[8+t][q];
      float cc = sigmoidf_(iv)*tanhf_(gv);
      float hh = sigmoidf_(ov)*tanhf_(cc);
      int ch = t*16 + lr;
      if (ok){
        out[PO_H + n*HL + ch] = hh;
        out[PO_C + n*HL + ch] = cc;
      }
      hlds[wv][lg*4+q][ch] = (_Float16)hh;
    }
  }
  __syncthreads();

  f16x8 ha0 = *reinterpret_cast<const f16x8*>(&hlds[wv][lr][lg*8]);
  f16x8 ha1 = *reinterpret_cast<const f16x8*>(&hlds[wv][lr][32 + lg*8]);

  #pragma unroll
  for (int t=0;t<12;t++){
    float b = bsum[192 + t*16 + lr];
    acc[t] = (f32x4){b,b,b,b};
  }
  #pragma unroll
  for (int t=0;t<12;t++){
    f16x8 b0 = wp[(24 + t*2+0)*64 + l];
    f16x8 b1 = wp[(24 + t*2+1)*64 + l];
    acc[t] = __builtin_amdgcn_mfma_f32_16x16x32_f16(ha0, b0, acc[t], 0, 0, 0);
    acc[t] = __builtin_amdgcn_mfma_f32_16x16x32_f16(ha1, b1, acc[t], 0, 0, 0);
  }

  #pragma unroll
  for (int q=0;q<4;q++){
    int n = n0 + lg*4 + q;
    bool ok = n < NN;
    float p = 0.f;
    #pragma unroll
    for (int t=0;t<4;t++){
      float iv = acc[t][q], gv = acc[4+t][q], ov = acc[8+t][q];
      float cc = sigmoidf_(iv)*tanhf_(gv);
      float hh = sigmoidf_(ov)*tanhf_(cc);
      int ch = t*16 + lr;
      if (ok){
        out[PO_H + NHL + n*HL + ch] = hh;
        out[PO_C + NHL + n*HL + ch] = cc;
      }
      p += hh * wo_t[t];
    }
    p += __shfl_xor(p, 1, 64);
    p += __shfl_xor(p, 2, 64);
    p += __shfl_xor(p, 4, 64);
    p += __shfl_xor(p, 8, 64);
    if (lr == 0 && ok) out[n] = p + bov;
  }
}

extern "C" void kernel_launch(void* const* d_in, const int* in_sizes, int n_in,
                              void* d_out, int out_size, void* d_ws, size_t ws_size,
                              hipStream_t stream){
  const float* x    = (const float*)d_in[0];
  const int*   ei   = (const int*)d_in[1];
  const float* W1   = (const float*)d_in[3];
  const float* as1  = (const float*)d_in[4];
  const float* ad1  = (const float*)d_in[5];
  const float* b1   = (const float*)d_in[6];
  const float* W2   = (const float*)d_in[7];
  const float* as2  = (const float*)d_in[8];
  const float* ad2  = (const float*)d_in[9];
  const float* b2   = (const float*)d_in[10];
  const float* Wih0 = (const float*)d_in[11];
  const float* bih0 = (const float*)d_in[13];
  const float* bhh0 = (const float*)d_in[14];
  const float* Wih1 = (const float*)d_in[15];
  const float* bih1 = (const float*)d_in[17];
  const float* bhh1 = (const float*)d_in[18];
  const float* Wo   = (const float*)d_in[19];
  const float* bo   = (const float*)d_in[20];
  float* out = (float*)d_out;

  float* ws   = (float*)d_ws;
  // layout (float offsets):
  __half* xw1h = (__half*)ws;                        // [0, 3.2M) : 6.4M halves (dead after agg1)
  unsigned int* sfifo = (unsigned int*)(ws + 3200000); // [3.2M, 4.05M) : dead after k_csr
  __half* xw2h = (__half*)(ws + 3200000);            // [3.2M, 4.8M) : 3.2M halves (written by gemm2h)
  _Float16* hb16 = (_Float16*)(ws + 4800000);        // [4.8M, 8.0M) : 6.4M halves (written by agg1)
  float* gbuf = ws;                                  // [0, 3.2M) : written by agg2 (xw1h dead then)
  float* s1   = ws + 9600000;                        // 200,000
  float* d1   = s1 + 200000;                         // -> 10.0M
  float* s2   = ws + 10000000;                       // 50,000
  float* d2   = s2 + 50000;                          // 50,000
  int*   deg  = (int*)(ws + 10100000);               // 50,000
  unsigned int* hist = (unsigned int*)(ws + 10150000);     // 16,384
  unsigned int* off  = (unsigned int*)(ws + 10170000);     // 16,384
  unsigned int* secstart = (unsigned int*)(ws + 10190000); // 65
  unsigned short* eidx16 = (unsigned short*)(ws + 10200000); // -> 11.81M
  _Float16* Wpk = (_Float16*)(ws + 11810000);        // 24,576 halves
  float* bsum = ws + 11823000;                       // 384 floats
  _Float16* W2B = (_Float16*)(ws + 11824000);        // 8,192 halves
  _Float16* W1B = (_Float16*)(ws + 11828096);        // 8,192 halves (end ~47.3 MB)

  k_hist  <<<NBLK1, 256, 0, stream>>>(ei, hist);
  k_hscan <<<1, 1024, 0, stream>>>(hist, off, secstart);
  k_sfill <<<NBLK1, 256, 0, stream>>>(ei, off, sfifo);
  k_csr   <<<NSEC, 1024, 0, stream>>>(secstart, sfifo, eidx16, deg);
  k_wt3   <<<162, 256, 0, stream>>>(Wih0, Wih1, bih0, bhh0, bih1, bhh1, W2, W1, Wpk, bsum, W2B, W1B);
  k_gemm1h<<<(NN/16 + G1W - 1)/G1W, 256, 0, stream>>>(x, W1B, as1, ad1, xw1h, s1, d1);
  k_agg1  <<<12500, 256, 0, stream>>>((const __half2*)xw1h, s1, d1, deg, eidx16, b1, (__half*)hb16);
  k_gemm2h<<<(NN/16 + G2W - 1)/G2W, 256, 0, stream>>>(hb16, W2B, as2, ad2, xw2h, s2, d2);
  k_agg2  <<<12500, 256, 0, stream>>>(xw2h, s2, d2, deg, eidx16, b2, gbuf);
  k_lstm6 <<<(NN + L6W*L6N - 1)/(L6W*L6N), 256, 0, stream>>>(gbuf, Wpk, bsum, Wo, bo, out);
}